// Round 2
// baseline (377.255 us; speedup 1.0000x reference)
//
#include <hip/hip_runtime.h>
#include <stdint.h>

typedef unsigned short u16;
typedef __bf16 bfrag __attribute__((ext_vector_type(8)));   // 8 bf16 = 4 VGPRs (MFMA A/B, K=32)
typedef short sh4 __attribute__((ext_vector_type(4)));      // 4 bf16 = 2 VGPRs (MFMA A/B, K=16)
typedef short sh8 __attribute__((ext_vector_type(8)));
typedef float f32x4 __attribute__((ext_vector_type(4)));    // MFMA C/D

#define LOG2E 1.44269504088896340736f

__device__ __forceinline__ u16 f2bf(float f) {
    unsigned u = __builtin_bit_cast(unsigned, f);
    u = (u + 0x7fffu + ((u >> 16) & 1u)) >> 16;
    return (u16)u;
}
__device__ __forceinline__ float bf2f(u16 x) {
    unsigned u = ((unsigned)x) << 16;
    return __builtin_bit_cast(float, u);
}

__device__ __forceinline__ void gl_lds16(const u16* g, u16* l) {
#if __has_builtin(__builtin_amdgcn_global_load_lds)
    __builtin_amdgcn_global_load_lds(
        (const __attribute__((address_space(1))) unsigned int*)g,
        (__attribute__((address_space(3))) unsigned int*)l, 16, 0, 0);
#else
    *(uint4*)l = *(const uint4*)g;
#endif
}

template <int N>
__device__ __forceinline__ void waitcnt_vm() {
    if constexpr (N == 0)      asm volatile("s_waitcnt vmcnt(0)" ::: "memory");
    else if constexpr (N == 3) asm volatile("s_waitcnt vmcnt(3)" ::: "memory");
    else if constexpr (N == 4) asm volatile("s_waitcnt vmcnt(4)" ::: "memory");
    else if constexpr (N == 6) asm volatile("s_waitcnt vmcnt(6)" ::: "memory");
    else if constexpr (N == 8) asm volatile("s_waitcnt vmcnt(8)" ::: "memory");
}

// PV micro-op: O^T[16d][16q] += V^T-frag (A) * P^T-frag (B), K=16
__device__ __forceinline__ f32x4 pv_mfma(sh4 v, sh4 p, f32x4 c) {
#if __has_builtin(__builtin_amdgcn_mfma_f32_16x16x16bf16_1k)
    return __builtin_amdgcn_mfma_f32_16x16x16bf16_1k(v, p, c, 0, 0, 0);
#else
    sh8 a = {v.x, v.y, v.z, v.w, 0, 0, 0, 0};
    sh8 b = {p.x, p.y, p.z, p.w, 0, 0, 0, 0};
    return __builtin_amdgcn_mfma_f32_16x16x32_bf16(
        __builtin_bit_cast(bfrag, a), __builtin_bit_cast(bfrag, b), c, 0, 0, 0);
#endif
}

// pack 4 f32 -> 4 bf16 via hardware v_cvt_pk_bf16_f32 (RNE), 2 instrs
__device__ __forceinline__ sh4 pack4(const f32x4& v) {
    uint2 u;
    asm("v_cvt_pk_bf16_f32 %0, %1, %2" : "=v"(u.x) : "v"(v[0]), "v"(v[1]));
    asm("v_cvt_pk_bf16_f32 %0, %1, %2" : "=v"(u.y) : "v"(v[2]), "v"(v[3]));
    return __builtin_bit_cast(sh4, u);
}

// ---------------- fp32 -> bf16 elementwise ----------------
__global__ __launch_bounds__(256) void cvt_f32_bf16(const float* __restrict__ s,
                                                    u16* __restrict__ d, int n4) {
    int i = blockIdx.x * 256 + threadIdx.x;
    if (i < n4) {
        float4 v = ((const float4*)s)[i];
        uint2 o;
        o.x = (unsigned)f2bf(v.x) | ((unsigned)f2bf(v.y) << 16);
        o.y = (unsigned)f2bf(v.z) | ((unsigned)f2bf(v.w) << 16);
        ((uint2*)d)[i] = o;
    }
}

// ---------------- transpose + convert ----------------
__global__ __launch_bounds__(256) void transpose_cvt(const float* __restrict__ src,
                                                     u16* __restrict__ dst,
                                                     int rows, int cols) {
    __shared__ float tile[32][33];
    int c0 = blockIdx.x * 32, r0 = blockIdx.y * 32;
    int tx = threadIdx.x, ty = threadIdx.y;
#pragma unroll
    for (int i = 0; i < 32; i += 8)
        tile[ty + i][tx] = src[(size_t)(r0 + ty + i) * cols + c0 + tx];
    __syncthreads();
#pragma unroll
    for (int i = 0; i < 32; i += 8)
        dst[(size_t)(c0 + ty + i) * rows + r0 + tx] = f2bf(tile[tx][ty + i]);
}

// ---------------- 8-wave GEMM, 3-buffer counted-vmcnt pipeline (T2+T4+T5) ----------
// C[M][N] = A[M][K] * B[N][K]^T.  BN = 256 fixed, BM template (256 for QKV-proj,
// 128 for O-proj so grid = 32x8 = 256 blocks -> every CU busy).
// Structure vs old 128^2 gemm_bt (2-barrier, vmcnt(0)-drain per K-step):
//  - 3 LDS buffers, BK=32: tile t computes from buf t%3 while tile t+2 stages into
//    buf (t+2)%3 (dead since tile t-1's end barrier -> stage issue is race-free).
//    Per-tile wait is a counted vmcnt(4): tile t+1's 4 loads stay in flight across
//    the barrier (T4; m218 counted-vs-drain0 = +38..73%). vmcnt(0) only at t=NT-2.
//  - bank-conflict-free swizzle: addr16(row,chunk) = (row>>1)*8 +
//    ((((row&1)<<2)|chunk) ^ ((row>>1)&7)); a ds_read_b128's 16 lanes hit all 8
//    bank groups (2/group = free, m136). Applied via pre-swizzled GLOBAL source
//    (global_load_lds dest must stay linear) + same XOR on the read side.
//  - lgkmcnt(0) before each barrier (no ds_read in flight when next stage lands),
//    s_setprio(1) around MFMA clusters (T5: staging/MFMA role-split now exists).
// Fragment content & C mapping identical to the proven old gemm_bt.
template <int BM, typename OutT>
__global__ __launch_bounds__(512, 2) void gemm_bt8(const u16* __restrict__ A,
                                                   const u16* __restrict__ B,
                                                   OutT* __restrict__ C,
                                                   int K, int ldc) {
    constexpr int BN = 256;
    constexpr int MF = BM / 32;     // A-frags per wave (rows/16 of the wave's BM/2)
    constexpr int NF = 4;           // B-frags per wave (64 cols)
    constexpr int LA = BM / 128;    // A stage loads per thread per tile
    constexpr int LB = 2;           // B stage loads per thread per tile
    constexpr int VW = LA + LB;     // vmem ops per staged tile

    __shared__ __align__(16) u16 As[3][BM * 32];
    __shared__ __align__(16) u16 Bs[3][BN * 32];

    const int tid = threadIdx.x;
    const int wid = tid >> 6, lane = tid & 63;
    const int quad = lane >> 4, l16 = lane & 15;
    const int wm = wid >> 2, wn = wid & 3;
    const int bm = blockIdx.x * BM, bn = blockIdx.y * BN;
    const int NT = K >> 5;

    // swizzled ds_read bases (u16 units); invariant across frag index (frag adds
    // 8 row-pairs = +512 u16, swizzle key (row>>1)&7 unchanged)
    const int arb = wm * (BM / 2) + l16;
    const int abase = (((arb >> 1) * 8) + ((((arb & 1) << 2) | quad) ^ ((arb >> 1) & 7))) * 8;
    const int brb = wn * 64 + l16;
    const int bbase = (((brb >> 1) * 8) + ((((brb & 1) << 2) | quad) ^ ((brb >> 1) & 7))) * 8;

    // stage source pointers: dest chunk c=(j*512+tid) is linear; invert the swizzle
    // on the global side: u=(c&7)^((c>>3)&7); row=((c>>3)<<1)|(u>>2); chunk=u&3.
    const u16* aSrc[LA];
    const u16* bSrc[LB];
#pragma unroll
    for (int j = 0; j < LA; ++j) {
        int c = j * 512 + tid;
        int u = (c & 7) ^ ((c >> 3) & 7);
        int row = ((c >> 3) << 1) | (u >> 2);
        aSrc[j] = A + (size_t)(bm + row) * K + (u & 3) * 8;
    }
#pragma unroll
    for (int j = 0; j < LB; ++j) {
        int c = j * 512 + tid;
        int u = (c & 7) ^ ((c >> 3) & 7);
        int row = ((c >> 3) << 1) | (u >> 2);
        bSrc[j] = B + (size_t)(bn + row) * K + (u & 3) * 8;
    }

    f32x4 acc[MF][NF] = {};

    // prologue: stage tile0 -> buf0, tile1 -> buf1; wait tile0, keep tile1 in flight
#pragma unroll
    for (int j = 0; j < LA; ++j) gl_lds16(aSrc[j], &As[0][(j * 512 + tid) * 8]);
#pragma unroll
    for (int j = 0; j < LB; ++j) gl_lds16(bSrc[j], &Bs[0][(j * 512 + tid) * 8]);
#pragma unroll
    for (int j = 0; j < LA; ++j) gl_lds16(aSrc[j] + 32, &As[1][(j * 512 + tid) * 8]);
#pragma unroll
    for (int j = 0; j < LB; ++j) gl_lds16(bSrc[j] + 32, &Bs[1][(j * 512 + tid) * 8]);
#pragma unroll
    for (int j = 0; j < LA; ++j) aSrc[j] += 64;  // point at tile 2
#pragma unroll
    for (int j = 0; j < LB; ++j) bSrc[j] += 64;
    waitcnt_vm<VW>();
    __builtin_amdgcn_s_barrier();
    asm volatile("" ::: "memory");

    int bt = 0, bs = 2;
    for (int t = 0; t < NT; ++t) {
        // stage tile t+2 into buf bs (= buffer consumed at tile t-1)
        if (t + 2 < NT) {
#pragma unroll
            for (int j = 0; j < LA; ++j) gl_lds16(aSrc[j], &As[bs][(j * 512 + tid) * 8]);
#pragma unroll
            for (int j = 0; j < LB; ++j) gl_lds16(bSrc[j], &Bs[bs][(j * 512 + tid) * 8]);
        }
#pragma unroll
        for (int j = 0; j < LA; ++j) aSrc[j] += 32;
#pragma unroll
        for (int j = 0; j < LB; ++j) bSrc[j] += 32;

        const u16* ab = &As[bt][0];
        const u16* bb = &Bs[bt][0];
        bfrag bf[NF];
#pragma unroll
        for (int nf = 0; nf < NF; ++nf) bf[nf] = *(const bfrag*)&bb[bbase + nf * 512];
        // half 1: frags 0..MF/2-1
        bfrag a0[MF / 2];
#pragma unroll
        for (int mf = 0; mf < MF / 2; ++mf) a0[mf] = *(const bfrag*)&ab[abase + mf * 512];
        __builtin_amdgcn_s_setprio(1);
#pragma unroll
        for (int mf = 0; mf < MF / 2; ++mf)
#pragma unroll
            for (int nf = 0; nf < NF; ++nf)
                acc[mf][nf] = __builtin_amdgcn_mfma_f32_16x16x32_bf16(a0[mf], bf[nf], acc[mf][nf], 0, 0, 0);
        __builtin_amdgcn_s_setprio(0);
        // half 2: frags MF/2..MF-1
        bfrag a1[MF / 2];
#pragma unroll
        for (int mf = 0; mf < MF / 2; ++mf)
            a1[mf] = *(const bfrag*)&ab[abase + (mf + MF / 2) * 512];
        __builtin_amdgcn_s_setprio(1);
#pragma unroll
        for (int mf = 0; mf < MF / 2; ++mf)
#pragma unroll
            for (int nf = 0; nf < NF; ++nf)
                acc[mf + MF / 2][nf] =
                    __builtin_amdgcn_mfma_f32_16x16x32_bf16(a1[mf], bf[nf], acc[mf + MF / 2][nf], 0, 0, 0);
        __builtin_amdgcn_s_setprio(0);

        // tile end: drain own ds_reads, counted vmcnt (tile t+1 lands; t+2 in flight)
        asm volatile("s_waitcnt lgkmcnt(0)" ::: "memory");
        if (t == NT - 2) waitcnt_vm<0>();
        else             waitcnt_vm<VW>();
        __builtin_amdgcn_s_barrier();
        asm volatile("" ::: "memory");
        bt = bt == 2 ? 0 : bt + 1;
        bs = bs == 2 ? 0 : bs + 1;
    }

#pragma unroll
    for (int mf = 0; mf < MF; ++mf)
#pragma unroll
        for (int nf = 0; nf < NF; ++nf)
#pragma unroll
            for (int r = 0; r < 4; ++r) {
                int row = bm + wm * (BM / 2) + mf * 16 + quad * 4 + r;
                int col = bn + wn * 64 + nf * 16 + l16;
                float v = acc[mf][nf][r];
                if constexpr (sizeof(OutT) == 2)
                    C[(size_t)row * ldc + col] = f2bf(v);
                else
                    C[(size_t)row * ldc + col] = v;
            }
}

// ---------------- RMSNorm + RoPE (q prescaled by softmax scale * log2e) ----------------
__global__ __launch_bounds__(256) void rmsrope(u16* __restrict__ qkv,
                                               const float* __restrict__ cosb,
                                               const float* __restrict__ sinb,
                                               const float* __restrict__ qw,
                                               const float* __restrict__ kw) {
    const float c1 = 0.08838834764831845f * LOG2E;
    int wave = threadIdx.x >> 6, lane = threadIdx.x & 63;
    int pi = blockIdx.x * 4 + wave;
    int m = pi / 20, hsel = pi % 20;
    int col0 = hsel < 16 ? hsel * 128 : 2048 + (hsel - 16) * 128;
    const float* w = hsel < 16 ? qw : kw;
    float sc = hsel < 16 ? c1 : 1.0f;
    int s = m & 2047;
    u16* p = qkv + (size_t)m * 3072 + col0;
    float x1 = bf2f(p[lane]), x2 = bf2f(p[lane + 64]);
    float ss = x1 * x1 + x2 * x2;
#pragma unroll
    for (int off = 32; off; off >>= 1) ss += __shfl_xor(ss, off, 64);
    float inv = rsqrtf(ss * (1.0f / 128.0f) + 1e-6f);
    float y1 = x1 * inv * w[lane], y2 = x2 * inv * w[lane + 64];
    const float* cp = cosb + (size_t)s * 128;
    const float* sp = sinb + (size_t)s * 128;
    float o1 = y1 * cp[lane] - y2 * sp[lane];
    float o2 = y2 * cp[lane + 64] + y1 * sp[lane + 64];
    p[lane] = f2bf(o1 * sc);
    p[lane + 64] = f2bf(o2 * sc);
}

// ---------------- V transpose ----------------
__global__ __launch_bounds__(256) void transpose_v(const u16* __restrict__ qkv,
                                                   u16* __restrict__ vT) {
    __shared__ u16 t[32][33];
    int bh = blockIdx.z, b = bh >> 2, kvh = bh & 3;
    int s0 = blockIdx.y * 32, d0 = blockIdx.x * 32;
    int tx = threadIdx.x, ty = threadIdx.y;
    const u16* src = qkv + (size_t)(b * 2048) * 3072 + 2560 + kvh * 128;
#pragma unroll
    for (int i = 0; i < 32; i += 8)
        t[ty + i][tx] = src[(size_t)(s0 + ty + i) * 3072 + d0 + tx];
    __syncthreads();
    u16* dst = vT + (size_t)bh * 128 * 2048;
#pragma unroll
    for (int i = 0; i < 32; i += 8)
        dst[(size_t)(d0 + ty + i) * 2048 + s0 + tx] = t[tx][ty + i];
}

// ---------------- stage one 64-wide KV tile (8x gl_lds16 per thread) ----------------
__device__ __forceinline__ void stage_tiles(const u16* __restrict__ qkv,
                                            const u16* __restrict__ vTbase,
                                            size_t rowBase, int kcol0, int kv0, int tid,
                                            u16* Ksb, u16* VsTb) {
#pragma unroll
    for (int i = 0; i < 4; ++i) {  // Ks: 64 rows x 16 chunks (pre-swizzled source)
        int c = i * 256 + tid, kv = c >> 4, cp2 = c & 15;
        gl_lds16(qkv + (rowBase + kv0 + kv) * 3072 + kcol0 + (cp2 ^ (kv & 15)) * 8,
                 &Ksb[c * 8]);
    }
#pragma unroll
    for (int i = 0; i < 4; ++i) {  // VsT: 128 rows x 8 chunks (pre-swizzled source)
        int c = i * 256 + tid, d = c >> 3, cp2 = c & 7;
        gl_lds16(vTbase + (size_t)d * 2048 + kv0 + (cp2 ^ (d & 7)) * 8, &VsTb[c * 8]);
    }
}

// ---------------- causal flash attention (v2: dbuf + counted vmcnt, cvt_pk, no-max) ----
__global__ __launch_bounds__(256) void attn_kernel(const u16* __restrict__ qkv,
                                                   const u16* __restrict__ vT,
                                                   u16* __restrict__ out) {
    __shared__ u16 Ks[2][64 * 128];    // [buf][kv][16B-chunk ^ (kv&15)]
    __shared__ u16 VsT[2][128 * 64];   // [buf][d][16B-chunk ^ (d&7)]
    const int tid = threadIdx.x, wave = tid >> 6, lane = tid & 63;
    const int quad = lane >> 4, l16 = lane & 15;
    const int bh = blockIdx.x, b = bh >> 4, h = bh & 15, kvh = h >> 2;
    const int pair = blockIdx.y;
    const size_t rowBase = (size_t)b * 2048;
    const int kcol0 = 2048 + kvh * 128;
    const u16* vTbase = vT + (size_t)(b * 4 + kvh) * 128 * 2048;

#pragma unroll 1
    for (int ph = 0; ph < 2; ++ph) {
        const int qt = ph == 0 ? pair : 31 - pair;
        const int qrow = qt * 64 + wave * 16 + l16;  // this lane's q row

        // Q B-frags (K=32): lane n=l16 holds d = ks*32 + quad*8 + j, contiguous 16B
        const u16* qp = qkv + (rowBase + qrow) * 3072 + h * 128 + quad * 8;
        bfrag qf[4];
#pragma unroll
        for (int ks = 0; ks < 4; ++ks) qf[ks] = *(const bfrag*)(qp + ks * 32);
        // Drain q loads NOW and re-materialize via asm so the compiler's waitcnt pass
        // never inserts a conservative vmcnt drain inside the pipelined loop.
        asm volatile("s_waitcnt vmcnt(0)" ::: "memory");
#pragma unroll
        for (int ks = 0; ks < 4; ++ks) {
            uint4 t = __builtin_bit_cast(uint4, qf[ks]);
            asm volatile("" : "+v"(t.x), "+v"(t.y), "+v"(t.z), "+v"(t.w));
            qf[ks] = __builtin_bit_cast(bfrag, t);
        }

        f32x4 o[8] = {};  // O^T: 8 d-tiles x 1 q-tile, C-layout (row=d, col=q=l16)
        float lrun = 0.f;

        // prologue: stage tile 0 into buffer 0 (8 outstanding vmem ops/thread)
        stage_tiles(qkv, vTbase, rowBase, kcol0, 0, tid, Ks[0], VsT[0]);

        for (int kt = 0; kt <= qt; ++kt) {
            const int cur = kt & 1;
            if (kt < qt) {
                // issue next tile's loads into the other buffer, then wait only for
                // the current tile (8 newest ops = next tile stay in flight)
                stage_tiles(qkv, vTbase, rowBase, kcol0, (kt + 1) * 64, tid,
                            Ks[cur ^ 1], VsT[cur ^ 1]);
                asm volatile("s_waitcnt vmcnt(8)" ::: "memory");
            } else {
                asm volatile("s_waitcnt vmcnt(0)" ::: "memory");
            }
            __builtin_amdgcn_s_barrier();
            asm volatile("" ::: "memory");

            const int kv0 = kt * 64;

            // S^T = K * Q^T : 4 kv-subtiles (m) x 1 q-subtile (scores already exp2-domain)
            f32x4 sa[4] = {};
            __builtin_amdgcn_s_setprio(1);
#pragma unroll
            for (int ks = 0; ks < 4; ++ks)
#pragma unroll
                for (int m = 0; m < 4; ++m) {
                    bfrag kf = *(const bfrag*)&Ks[cur][((m * 16 + l16) * 16 + ((ks * 4 + quad) ^ l16)) * 8];
                    sa[m] = __builtin_amdgcn_mfma_f32_16x16x32_bf16(kf, qf[ks], sa[m], 0, 0, 0);
                }
            __builtin_amdgcn_s_setprio(0);

            // no-max softmax: p = exp2(s); masked lanes -> 0 via -3e38 (underflows)
            if (kv0 + 63 > qt * 64 + wave * 16) {  // only the diagonal tile needs masking
#pragma unroll
                for (int m = 0; m < 4; ++m)
#pragma unroll
                    for (int r = 0; r < 4; ++r)
                        if (kv0 + m * 16 + quad * 4 + r > qrow) sa[m][r] = -3e38f;
            }
            float rs = 0.f;
#pragma unroll
            for (int m = 0; m < 4; ++m)
#pragma unroll
                for (int r = 0; r < 4; ++r) {
                    float pe = exp2f(sa[m][r]);
                    sa[m][r] = pe;
                    rs += pe;
                }
            rs += __shfl_xor(rs, 16, 64);
            rs += __shfl_xor(rs, 32, 64);
            lrun += rs;

            // O^T += V^T * P^T  (K=16 MFMA; P^T C-layout IS the B-layout)
            sh4 pf[4];
#pragma unroll
            for (int m = 0; m < 4; ++m) pf[m] = pack4(sa[m]);
            __builtin_amdgcn_s_setprio(1);
#pragma unroll
            for (int k2 = 0; k2 < 4; ++k2) {
#pragma unroll
                for (int dt = 0; dt < 8; ++dt) {
                    int d = dt * 16 + l16;
                    int ch = k2 * 2 + (quad >> 1);
                    sh4 vf = *(const sh4*)&VsT[cur][(d * 8 + (ch ^ (l16 & 7))) * 8 + (quad & 1) * 4];
                    o[dt] = pv_mfma(vf, pf[k2], o[dt]);
                }
            }
            __builtin_amdgcn_s_setprio(0);
            asm volatile("" ::: "memory");
            __builtin_amdgcn_s_barrier();  // all reads of buf[cur] done before overwrite
        }

        // epilogue: normalize, pack 4 bf16 (consecutive d), store 8B per (lane, dtile)
        float inv = 1.0f / lrun;
        size_t orow = (rowBase + qrow) * 2048 + h * 128 + quad * 4;
#pragma unroll
        for (int dt = 0; dt < 8; ++dt) {
            float a0 = o[dt][0] * inv, a1 = o[dt][1] * inv;
            float a2 = o[dt][2] * inv, a3 = o[dt][3] * inv;
            uint2 pk;
            asm("v_cvt_pk_bf16_f32 %0, %1, %2" : "=v"(pk.x) : "v"(a0), "v"(a1));
            asm("v_cvt_pk_bf16_f32 %0, %1, %2" : "=v"(pk.y) : "v"(a2), "v"(a3));
            *(uint2*)(out + orow + dt * 16) = pk;
        }
    }
}

extern "C" void kernel_launch(void* const* d_in, const int* in_sizes, int n_in,
                              void* d_out, int out_size, void* d_ws, size_t ws_size,
                              hipStream_t stream) {
    const float* hs   = (const float*)d_in[0];
    const float* cosb = (const float*)d_in[1];
    const float* sinb = (const float*)d_in[2];
    const float* Wq = (const float*)d_in[4];
    const float* Wk = (const float*)d_in[5];
    const float* Wv = (const float*)d_in[6];
    const float* Wo = (const float*)d_in[7];
    const float* qw = (const float*)d_in[8];
    const float* kw = (const float*)d_in[9];
    float* out = (float*)d_out;

    char* ws = (char*)d_ws;
    u16* hsb   = (u16*)(ws + 0);          // 16 MB: hs bf16; later reused as attn-out bf16
    u16* wqkvT = (u16*)(ws + 16777216);   // 12 MB
    u16* woT   = (u16*)(ws + 29360128);   // 8 MB
    u16* qkv   = (u16*)(ws + 37748736);   // 24 MB
    u16* vT    = (u16*)(ws + 62914560);   // 4 MB

    dim3 tb(32, 8);
    cvt_f32_bf16<<<8192, 256, 0, stream>>>(hs, hsb, 2097152);
    transpose_cvt<<<dim3(64, 64), tb, 0, stream>>>(Wq, wqkvT, 2048, 2048);
    transpose_cvt<<<dim3(16, 64), tb, 0, stream>>>(Wk, wqkvT + (size_t)2048 * 2048, 2048, 512);
    transpose_cvt<<<dim3(16, 64), tb, 0, stream>>>(Wv, wqkvT + (size_t)2560 * 2048, 2048, 512);
    transpose_cvt<<<dim3(64, 64), tb, 0, stream>>>(Wo, woT, 2048, 2048);

    // QKV projection: M=4096, N=3072, K=2048 -> 16x12 = 192 blocks of 512
    gemm_bt8<256, u16><<<dim3(16, 12), 512, 0, stream>>>(hsb, wqkvT, qkv, 2048, 3072);

    rmsrope<<<20480, 256, 0, stream>>>(qkv, cosb, sinb, qw, kw);
    transpose_v<<<dim3(4, 64, 8), tb, 0, stream>>>(qkv, vT);

    attn_kernel<<<dim3(32, 16), 256, 0, stream>>>(qkv, vT, hsb);

    // O projection: M=4096, N=2048, K=2048 -> BM=128: 32x8 = 256 blocks (all CUs)
    gemm_bt8<128, float><<<dim3(32, 8), 512, 0, stream>>>(hsb, woT, out, 2048, 2048);
}

// Round 4
// 348.527 us; speedup vs baseline: 1.0824x; 1.0824x over previous
//
#include <hip/hip_runtime.h>
#include <stdint.h>

typedef unsigned short u16;
typedef __bf16 bfrag __attribute__((ext_vector_type(8)));   // 8 bf16 = 4 VGPRs (MFMA A/B, K=32)
typedef short sh4 __attribute__((ext_vector_type(4)));      // 4 bf16 = 2 VGPRs (MFMA A/B, K=16)
typedef short sh8 __attribute__((ext_vector_type(8)));
typedef float f32x4 __attribute__((ext_vector_type(4)));    // MFMA C/D

#define LOG2E 1.44269504088896340736f

__device__ __forceinline__ u16 f2bf(float f) {
    unsigned u = __builtin_bit_cast(unsigned, f);
    u = (u + 0x7fffu + ((u >> 16) & 1u)) >> 16;
    return (u16)u;
}
__device__ __forceinline__ float bf2f(u16 x) {
    unsigned u = ((unsigned)x) << 16;
    return __builtin_bit_cast(float, u);
}

__device__ __forceinline__ void gl_lds16(const u16* g, u16* l) {
#if __has_builtin(__builtin_amdgcn_global_load_lds)
    __builtin_amdgcn_global_load_lds(
        (const __attribute__((address_space(1))) unsigned int*)g,
        (__attribute__((address_space(3))) unsigned int*)l, 16, 0, 0);
#else
    *(uint4*)l = *(const uint4*)g;
#endif
}

template <int N>
__device__ __forceinline__ void waitcnt_vm() {
    if constexpr (N == 0)      asm volatile("s_waitcnt vmcnt(0)" ::: "memory");
    else if constexpr (N == 6) asm volatile("s_waitcnt vmcnt(6)" ::: "memory");
    else if constexpr (N == 8) asm volatile("s_waitcnt vmcnt(8)" ::: "memory");
}

// PV micro-op: O^T[16d][16q] += V^T-frag (A) * P^T-frag (B), K=16
__device__ __forceinline__ f32x4 pv_mfma(sh4 v, sh4 p, f32x4 c) {
#if __has_builtin(__builtin_amdgcn_mfma_f32_16x16x16bf16_1k)
    return __builtin_amdgcn_mfma_f32_16x16x16bf16_1k(v, p, c, 0, 0, 0);
#else
    sh8 a = {v.x, v.y, v.z, v.w, 0, 0, 0, 0};
    sh8 b = {p.x, p.y, p.z, p.w, 0, 0, 0, 0};
    return __builtin_amdgcn_mfma_f32_16x16x32_bf16(
        __builtin_bit_cast(bfrag, a), __builtin_bit_cast(bfrag, b), c, 0, 0, 0);
#endif
}

// pack 4 f32 -> 4 bf16 via hardware v_cvt_pk_bf16_f32 (RNE), 2 instrs
__device__ __forceinline__ sh4 pack4(const f32x4& v) {
    uint2 u;
    asm("v_cvt_pk_bf16_f32 %0, %1, %2" : "=v"(u.x) : "v"(v[0]), "v"(v[1]));
    asm("v_cvt_pk_bf16_f32 %0, %1, %2" : "=v"(u.y) : "v"(v[2]), "v"(v[3]));
    return __builtin_bit_cast(sh4, u);
}

// ---------------- fp32 -> bf16 elementwise ----------------
__global__ __launch_bounds__(256) void cvt_f32_bf16(const float* __restrict__ s,
                                                    u16* __restrict__ d, int n4) {
    int i = blockIdx.x * 256 + threadIdx.x;
    if (i < n4) {
        float4 v = ((const float4*)s)[i];
        uint2 o;
        o.x = (unsigned)f2bf(v.x) | ((unsigned)f2bf(v.y) << 16);
        o.y = (unsigned)f2bf(v.z) | ((unsigned)f2bf(v.w) << 16);
        ((uint2*)d)[i] = o;
    }
}

// ---------------- transpose + convert ----------------
__global__ __launch_bounds__(256) void transpose_cvt(const float* __restrict__ src,
                                                     u16* __restrict__ dst,
                                                     int rows, int cols) {
    __shared__ float tile[32][33];
    int c0 = blockIdx.x * 32, r0 = blockIdx.y * 32;
    int tx = threadIdx.x, ty = threadIdx.y;
#pragma unroll
    for (int i = 0; i < 32; i += 8)
        tile[ty + i][tx] = src[(size_t)(r0 + ty + i) * cols + c0 + tx];
    __syncthreads();
#pragma unroll
    for (int i = 0; i < 32; i += 8)
        dst[(size_t)(c0 + ty + i) * rows + r0 + tx] = f2bf(tile[tx][ty + i]);
}

// ---------------- phase-split GEMM: C[M][N] = A[M][K]*B[N][K]^T --------------------
// BM=256 x BN=128, BK=64, 512 thr (8 waves 4Mx2N, per-wave 64x64), dbuf LDS 96 KB.
// Schedule per K-tile t (buf = t&1), derived race-free:
//   RD all 16 frags (ks0+ks1) -> regs           (compiler fine-grained lgkmcnt)
//   MFMA ks0 (16)                                (overlaps the ks1 ds_reads)
//   lgkmcnt(0); barrier                          -> ALL waves' reads of buf done
//   STAGE tile t+2 -> buf (6 gl_lds, DMA)        (buf just became writable)
//   MFMA ks1 (16)                                (registers only; DMA in background)
//   vmcnt(6); barrier                            -> tile t+1 resident; t+2's 6 in flight
// Loads span a full tile (~1500cy) before being waited on (T4 counted-vmcnt); only
// 2 barriers/tile; setprio(1) around MFMA clusters (T5). LDS swizzle: chunk' =
// chunk ^ (row&7) -> ds_read_b128 16 lanes hit 8 chunk-slots x2 = conflict-free.
// global_load_lds dest stays linear; inverse XOR applied on the global source.
template <typename OutT>
__global__ __launch_bounds__(512, 2) void gemm_p4(const u16* __restrict__ A,
                                                  const u16* __restrict__ B,
                                                  OutT* __restrict__ C,
                                                  int K, int ldc) {
    constexpr int BM = 256, BN = 128;
    __shared__ __align__(16) u16 As[2][BM * 64];
    __shared__ __align__(16) u16 Bs[2][BN * 64];
    const int tid = threadIdx.x;
    const int wid = tid >> 6, lane = tid & 63;
    const int quad = lane >> 4, l16 = lane & 15;
    const int wm = wid >> 1, wn = wid & 1;
    const int bm = blockIdx.x * BM, bn = blockIdx.y * BN;
    const int NT = K >> 6;

    // stage source pointers (linear LDS dest chunk c -> inverse-swizzled global src)
    const u16* aSrc[4];
    const u16* bSrc[2];
#pragma unroll
    for (int j = 0; j < 4; ++j) {
        int c = j * 512 + tid, row = c >> 3, ch = c & 7;
        aSrc[j] = A + (size_t)(bm + row) * K + (ch ^ (row & 7)) * 8;
    }
#pragma unroll
    for (int j = 0; j < 2; ++j) {
        int c = j * 512 + tid, row = c >> 3, ch = c & 7;
        bSrc[j] = B + (size_t)(bn + row) * K + (ch ^ (row & 7)) * 8;
    }

    // ds_read bases (u16 units); row stride 64, frag stride 16 rows = 1024
    const int swz = l16 & 7;
    const int aBase = (wm * 64 + l16) * 64;
    const int bBase = (wn * 64 + l16) * 64;
    const int c0 = (quad ^ swz) * 8;          // ks=0 swizzled chunk offset
    const int c1 = ((4 | quad) ^ swz) * 8;    // ks=1

    f32x4 acc[4][4] = {};

    // prologue: stage tile0 -> buf0, tile1 -> buf1; wait tile0 (6 newest in flight)
#pragma unroll
    for (int j = 0; j < 4; ++j) gl_lds16(aSrc[j], &As[0][(j * 512 + tid) * 8]);
#pragma unroll
    for (int j = 0; j < 2; ++j) gl_lds16(bSrc[j], &Bs[0][(j * 512 + tid) * 8]);
#pragma unroll
    for (int j = 0; j < 4; ++j) gl_lds16(aSrc[j] + 64, &As[1][(j * 512 + tid) * 8]);
#pragma unroll
    for (int j = 0; j < 2; ++j) gl_lds16(bSrc[j] + 64, &Bs[1][(j * 512 + tid) * 8]);
    waitcnt_vm<6>();
    __builtin_amdgcn_s_barrier();
    asm volatile("" ::: "memory");

    int koff = 128;  // K-offset of tile t+2
    for (int t = 0; t < NT; ++t) {
        const u16* ab = &As[t & 1][0];
        const u16* bb = &Bs[t & 1][0];

        bfrag a0[4], b0[4], a1[4], b1[4];
#pragma unroll
        for (int mf = 0; mf < 4; ++mf) a0[mf] = *(const bfrag*)&ab[aBase + mf * 1024 + c0];
#pragma unroll
        for (int nf = 0; nf < 4; ++nf) b0[nf] = *(const bfrag*)&bb[bBase + nf * 1024 + c0];
#pragma unroll
        for (int mf = 0; mf < 4; ++mf) a1[mf] = *(const bfrag*)&ab[aBase + mf * 1024 + c1];
#pragma unroll
        for (int nf = 0; nf < 4; ++nf) b1[nf] = *(const bfrag*)&bb[bBase + nf * 1024 + c1];

        __builtin_amdgcn_s_setprio(1);
#pragma unroll
        for (int mf = 0; mf < 4; ++mf)
#pragma unroll
            for (int nf = 0; nf < 4; ++nf)
                acc[mf][nf] = __builtin_amdgcn_mfma_f32_16x16x32_bf16(a0[mf], b0[nf], acc[mf][nf], 0, 0, 0);
        __builtin_amdgcn_s_setprio(0);

        // all waves' reads of this buffer complete -> buffer becomes DMA-writable
        asm volatile("s_waitcnt lgkmcnt(0)" ::: "memory");
        __builtin_amdgcn_s_barrier();
        asm volatile("" ::: "memory");

        if (t + 2 < NT) {
#pragma unroll
            for (int j = 0; j < 4; ++j) gl_lds16(aSrc[j] + koff, &As[t & 1][(j * 512 + tid) * 8]);
#pragma unroll
            for (int j = 0; j < 2; ++j) gl_lds16(bSrc[j] + koff, &Bs[t & 1][(j * 512 + tid) * 8]);
            koff += 64;
        }

        __builtin_amdgcn_s_setprio(1);
#pragma unroll
        for (int mf = 0; mf < 4; ++mf)
#pragma unroll
            for (int nf = 0; nf < 4; ++nf)
                acc[mf][nf] = __builtin_amdgcn_mfma_f32_16x16x32_bf16(a1[mf], b1[nf], acc[mf][nf], 0, 0, 0);
        __builtin_amdgcn_s_setprio(0);

        if (t + 2 < NT)      waitcnt_vm<6>();  // t+1 resident; t+2's 6 stay in flight
        else if (t + 1 < NT) waitcnt_vm<0>();  // drain for the last tile
        if (t + 1 < NT) {
            __builtin_amdgcn_s_barrier();
            asm volatile("" ::: "memory");
        }
    }

#pragma unroll
    for (int mf = 0; mf < 4; ++mf)
#pragma unroll
        for (int nf = 0; nf < 4; ++nf)
#pragma unroll
            for (int r = 0; r < 4; ++r) {
                int row = bm + wm * 64 + mf * 16 + quad * 4 + r;
                int col = bn + wn * 64 + nf * 16 + l16;
                float v = acc[mf][nf][r];
                if constexpr (sizeof(OutT) == 2)
                    C[(size_t)row * ldc + col] = f2bf(v);
                else
                    C[(size_t)row * ldc + col] = v;
            }
}

// ---------------- RMSNorm + RoPE (q prescaled by softmax scale * log2e) ----------------
__global__ __launch_bounds__(256) void rmsrope(u16* __restrict__ qkv,
                                               const float* __restrict__ cosb,
                                               const float* __restrict__ sinb,
                                               const float* __restrict__ qw,
                                               const float* __restrict__ kw) {
    const float c1 = 0.08838834764831845f * LOG2E;
    int wave = threadIdx.x >> 6, lane = threadIdx.x & 63;
    int pi = blockIdx.x * 4 + wave;
    int m = pi / 20, hsel = pi % 20;
    int col0 = hsel < 16 ? hsel * 128 : 2048 + (hsel - 16) * 128;
    const float* w = hsel < 16 ? qw : kw;
    float sc = hsel < 16 ? c1 : 1.0f;
    int s = m & 2047;
    u16* p = qkv + (size_t)m * 3072 + col0;
    float x1 = bf2f(p[lane]), x2 = bf2f(p[lane + 64]);
    float ss = x1 * x1 + x2 * x2;
#pragma unroll
    for (int off = 32; off; off >>= 1) ss += __shfl_xor(ss, off, 64);
    float inv = rsqrtf(ss * (1.0f / 128.0f) + 1e-6f);
    float y1 = x1 * inv * w[lane], y2 = x2 * inv * w[lane + 64];
    const float* cp = cosb + (size_t)s * 128;
    const float* sp = sinb + (size_t)s * 128;
    float o1 = y1 * cp[lane] - y2 * sp[lane];
    float o2 = y2 * cp[lane + 64] + y1 * sp[lane + 64];
    p[lane] = f2bf(o1 * sc);
    p[lane + 64] = f2bf(o2 * sc);
}

// ---------------- V transpose ----------------
__global__ __launch_bounds__(256) void transpose_v(const u16* __restrict__ qkv,
                                                   u16* __restrict__ vT) {
    __shared__ u16 t[32][33];
    int bh = blockIdx.z, b = bh >> 2, kvh = bh & 3;
    int s0 = blockIdx.y * 32, d0 = blockIdx.x * 32;
    int tx = threadIdx.x, ty = threadIdx.y;
    const u16* src = qkv + (size_t)(b * 2048) * 3072 + 2560 + kvh * 128;
#pragma unroll
    for (int i = 0; i < 32; i += 8)
        t[ty + i][tx] = src[(size_t)(s0 + ty + i) * 3072 + d0 + tx];
    __syncthreads();
    u16* dst = vT + (size_t)bh * 128 * 2048;
#pragma unroll
    for (int i = 0; i < 32; i += 8)
        dst[(size_t)(d0 + ty + i) * 2048 + s0 + tx] = t[tx][ty + i];
}

// ---------------- stage one 64-wide KV tile (8x gl_lds16 per thread) ----------------
__device__ __forceinline__ void stage_tiles(const u16* __restrict__ qkv,
                                            const u16* __restrict__ vTbase,
                                            size_t rowBase, int kcol0, int kv0, int tid,
                                            u16* Ksb, u16* VsTb) {
#pragma unroll
    for (int i = 0; i < 4; ++i) {  // Ks: 64 rows x 16 chunks (pre-swizzled source)
        int c = i * 256 + tid, kv = c >> 4, cp2 = c & 15;
        gl_lds16(qkv + (rowBase + kv0 + kv) * 3072 + kcol0 + (cp2 ^ (kv & 15)) * 8,
                 &Ksb[c * 8]);
    }
#pragma unroll
    for (int i = 0; i < 4; ++i) {  // VsT: 128 rows x 8 chunks (pre-swizzled source)
        int c = i * 256 + tid, d = c >> 3, cp2 = c & 7;
        gl_lds16(vTbase + (size_t)d * 2048 + kv0 + (cp2 ^ (d & 7)) * 8, &VsTb[c * 8]);
    }
}

// ---------------- causal flash attention (v2: dbuf + counted vmcnt, cvt_pk, no-max) ----
__global__ __launch_bounds__(256) void attn_kernel(const u16* __restrict__ qkv,
                                                   const u16* __restrict__ vT,
                                                   u16* __restrict__ out) {
    __shared__ u16 Ks[2][64 * 128];    // [buf][kv][16B-chunk ^ (kv&15)]
    __shared__ u16 VsT[2][128 * 64];   // [buf][d][16B-chunk ^ (d&7)]
    const int tid = threadIdx.x, wave = tid >> 6, lane = tid & 63;
    const int quad = lane >> 4, l16 = lane & 15;
    const int bh = blockIdx.x, b = bh >> 4, h = bh & 15, kvh = h >> 2;
    const int pair = blockIdx.y;
    const size_t rowBase = (size_t)b * 2048;
    const int kcol0 = 2048 + kvh * 128;
    const u16* vTbase = vT + (size_t)(b * 4 + kvh) * 128 * 2048;

#pragma unroll 1
    for (int ph = 0; ph < 2; ++ph) {
        const int qt = ph == 0 ? pair : 31 - pair;
        const int qrow = qt * 64 + wave * 16 + l16;  // this lane's q row

        // Q B-frags (K=32): lane n=l16 holds d = ks*32 + quad*8 + j, contiguous 16B
        const u16* qp = qkv + (rowBase + qrow) * 3072 + h * 128 + quad * 8;
        bfrag qf[4];
#pragma unroll
        for (int ks = 0; ks < 4; ++ks) qf[ks] = *(const bfrag*)(qp + ks * 32);
        // Drain q loads NOW and re-materialize via asm so the compiler's waitcnt pass
        // never inserts a conservative vmcnt drain inside the pipelined loop.
        asm volatile("s_waitcnt vmcnt(0)" ::: "memory");
#pragma unroll
        for (int ks = 0; ks < 4; ++ks) {
            uint4 t = __builtin_bit_cast(uint4, qf[ks]);
            asm volatile("" : "+v"(t.x), "+v"(t.y), "+v"(t.z), "+v"(t.w));
            qf[ks] = __builtin_bit_cast(bfrag, t);
        }

        f32x4 o[8] = {};  // O^T: 8 d-tiles x 1 q-tile, C-layout (row=d, col=q=l16)
        float lrun = 0.f;

        // prologue: stage tile 0 into buffer 0 (8 outstanding vmem ops/thread)
        stage_tiles(qkv, vTbase, rowBase, kcol0, 0, tid, Ks[0], VsT[0]);

        for (int kt = 0; kt <= qt; ++kt) {
            const int cur = kt & 1;
            if (kt < qt) {
                // issue next tile's loads into the other buffer, then wait only for
                // the current tile (8 newest ops = next tile stay in flight)
                stage_tiles(qkv, vTbase, rowBase, kcol0, (kt + 1) * 64, tid,
                            Ks[cur ^ 1], VsT[cur ^ 1]);
                asm volatile("s_waitcnt vmcnt(8)" ::: "memory");
            } else {
                asm volatile("s_waitcnt vmcnt(0)" ::: "memory");
            }
            __builtin_amdgcn_s_barrier();
            asm volatile("" ::: "memory");

            const int kv0 = kt * 64;

            // S^T = K * Q^T : 4 kv-subtiles (m) x 1 q-subtile (scores already exp2-domain)
            f32x4 sa[4] = {};
            __builtin_amdgcn_s_setprio(1);
#pragma unroll
            for (int ks = 0; ks < 4; ++ks)
#pragma unroll
                for (int m = 0; m < 4; ++m) {
                    bfrag kf = *(const bfrag*)&Ks[cur][((m * 16 + l16) * 16 + ((ks * 4 + quad) ^ l16)) * 8];
                    sa[m] = __builtin_amdgcn_mfma_f32_16x16x32_bf16(kf, qf[ks], sa[m], 0, 0, 0);
                }
            __builtin_amdgcn_s_setprio(0);

            // no-max softmax: p = exp2(s); masked lanes -> 0 via -3e38 (underflows)
            if (kv0 + 63 > qt * 64 + wave * 16) {  // only the diagonal tile needs masking
#pragma unroll
                for (int m = 0; m < 4; ++m)
#pragma unroll
                    for (int r = 0; r < 4; ++r)
                        if (kv0 + m * 16 + quad * 4 + r > qrow) sa[m][r] = -3e38f;
            }
            float rs = 0.f;
#pragma unroll
            for (int m = 0; m < 4; ++m)
#pragma unroll
                for (int r = 0; r < 4; ++r) {
                    float pe = exp2f(sa[m][r]);
                    sa[m][r] = pe;
                    rs += pe;
                }
            rs += __shfl_xor(rs, 16, 64);
            rs += __shfl_xor(rs, 32, 64);
            lrun += rs;

            // O^T += V^T * P^T  (K=16 MFMA; P^T C-layout IS the B-layout)
            sh4 pf[4];
#pragma unroll
            for (int m = 0; m < 4; ++m) pf[m] = pack4(sa[m]);
            __builtin_amdgcn_s_setprio(1);
#pragma unroll
            for (int k2 = 0; k2 < 4; ++k2) {
#pragma unroll
                for (int dt = 0; dt < 8; ++dt) {
                    int d = dt * 16 + l16;
                    int ch = k2 * 2 + (quad >> 1);
                    sh4 vf = *(const sh4*)&VsT[cur][(d * 8 + (ch ^ (l16 & 7))) * 8 + (quad & 1) * 4];
                    o[dt] = pv_mfma(vf, pf[k2], o[dt]);
                }
            }
            __builtin_amdgcn_s_setprio(0);
            asm volatile("" ::: "memory");
            __builtin_amdgcn_s_barrier();  // all reads of buf[cur] done before overwrite
        }

        // epilogue: normalize, pack 4 bf16 (consecutive d), store 8B per (lane, dtile)
        float inv = 1.0f / lrun;
        size_t orow = (rowBase + qrow) * 2048 + h * 128 + quad * 4;
#pragma unroll
        for (int dt = 0; dt < 8; ++dt) {
            float a0 = o[dt][0] * inv, a1 = o[dt][1] * inv;
            float a2 = o[dt][2] * inv, a3 = o[dt][3] * inv;
            uint2 pk;
            asm("v_cvt_pk_bf16_f32 %0, %1, %2" : "=v"(pk.x) : "v"(a0), "v"(a1));
            asm("v_cvt_pk_bf16_f32 %0, %1, %2" : "=v"(pk.y) : "v"(a2), "v"(a3));
            *(uint2*)(out + orow + dt * 16) = pk;
        }
    }
}

extern "C" void kernel_launch(void* const* d_in, const int* in_sizes, int n_in,
                              void* d_out, int out_size, void* d_ws, size_t ws_size,
                              hipStream_t stream) {
    const float* hs   = (const float*)d_in[0];
    const float* cosb = (const float*)d_in[1];
    const float* sinb = (const float*)d_in[2];
    const float* Wq = (const float*)d_in[4];
    const float* Wk = (const float*)d_in[5];
    const float* Wv = (const float*)d_in[6];
    const float* Wo = (const float*)d_in[7];
    const float* qw = (const float*)d_in[8];
    const float* kw = (const float*)d_in[9];
    float* out = (float*)d_out;

    char* ws = (char*)d_ws;
    u16* hsb   = (u16*)(ws + 0);          // 16 MB: hs bf16; later reused as attn-out bf16
    u16* wqkvT = (u16*)(ws + 16777216);   // 12 MB
    u16* woT   = (u16*)(ws + 29360128);   // 8 MB
    u16* qkv   = (u16*)(ws + 37748736);   // 24 MB
    u16* vT    = (u16*)(ws + 62914560);   // 4 MB

    dim3 tb(32, 8);
    cvt_f32_bf16<<<8192, 256, 0, stream>>>(hs, hsb, 2097152);
    transpose_cvt<<<dim3(64, 64), tb, 0, stream>>>(Wq, wqkvT, 2048, 2048);
    transpose_cvt<<<dim3(16, 64), tb, 0, stream>>>(Wk, wqkvT + (size_t)2048 * 2048, 2048, 512);
    transpose_cvt<<<dim3(16, 64), tb, 0, stream>>>(Wv, wqkvT + (size_t)2560 * 2048, 2048, 512);
    transpose_cvt<<<dim3(64, 64), tb, 0, stream>>>(Wo, woT, 2048, 2048);

    // QKV projection: M=4096, N=3072, K=2048 -> 16x24 = 384 blocks of 512
    gemm_p4<u16><<<dim3(16, 24), 512, 0, stream>>>(hsb, wqkvT, qkv, 2048, 3072);

    rmsrope<<<20480, 256, 0, stream>>>(qkv, cosb, sinb, qw, kw);
    transpose_v<<<dim3(4, 64, 8), tb, 0, stream>>>(qkv, vT);

    attn_kernel<<<dim3(32, 16), 256, 0, stream>>>(qkv, vT, hsb);

    // O projection: M=4096, N=2048, K=2048 -> 16x16 = 256 blocks (all CUs busy)
    gemm_p4<float><<<dim3(16, 16), 512, 0, stream>>>(hsb, woT, out, 2048, 2048);
}